// Round 2
// baseline (2950.033 us; speedup 1.0000x reference)
//
#include <hip/hip_runtime.h>
#include <stdint.h>

#define E_EDGES 400000
#define N_NODES 100000

// ---------------- workspace layout (bytes) ----------------
#define OSLR  ((size_t)524288)                         // slr packed bf16, u32[E*64]
#define ONW   (OSLR + (size_t)E_EDGES * 64 * 4)        // float[N]  node_weights
#define OMI   (ONW + (size_t)N_NODES * 4)              // float[N]  m_inv
#define OII   (OMI + (size_t)N_NODES * 4)              // float[N]  i_inv
#define ODE   (OII + (size_t)N_NODES * 4)              // float[N]  de_out
#define OFS   (ODE + (size_t)N_NODES * 4)              // float[3N] fij sums
#define OTS   (OFS + (size_t)N_NODES * 12)             // float[3N] tau sums
#define WSEND (OTS + (size_t)N_NODES * 12)

// ---------------- helpers ----------------
__device__ __forceinline__ float bfu_lo(uint32_t u) { return __uint_as_float(u << 16); }
__device__ __forceinline__ float bfu_hi(uint32_t u) { return __uint_as_float(u & 0xffff0000u); }
__device__ __forceinline__ uint32_t f2bf16(float f) {
  uint32_t x = __float_as_uint(f);
  return (x + 0x7fffu + ((x >> 16) & 1u)) >> 16;   // RNE
}
__device__ __forceinline__ float wave_sum64(float v) {
#pragma unroll
  for (int off = 32; off > 0; off >>= 1) v += __shfl_xor(v, off, 64);
  return v;
}

// acc[8] pairs: a0 -> out col = lane, a1 -> out col = lane+64.
// W: fp32 row-major (Ka rows x 128 cols), read directly (L2-resident).
__device__ __forceinline__ void gemv8(const float* __restrict__ W,
                                      const float* __restrict__ xb, int xstride,
                                      int Ka, int lane, float* a0, float* a1) {
#pragma unroll 2
  for (int i = 0; i < Ka; i += 4) {
    float w0[4], w1[4];
#pragma unroll
    for (int u = 0; u < 4; ++u) {
      w0[u] = W[(size_t)(i + u) * 128 + lane];
      w1[u] = W[(size_t)(i + u) * 128 + 64 + lane];
    }
#pragma unroll
    for (int r = 0; r < 8; ++r) {
#pragma unroll
      for (int u = 0; u < 4; ++u) {
        float xv = xb[r * xstride + i + u];
        a0[r] = fmaf(xv, w0[u], a0[r]);
        a1[r] = fmaf(xv, w1[u], a1[r]);
      }
    }
  }
}

__device__ __forceinline__ void layernorm8(float* y0, float* y1, float g0, float g1,
                                           float be0, float be1) {
#pragma unroll
  for (int r = 0; r < 8; ++r) {
    float s  = wave_sum64(y0[r] + y1[r]);
    float s2 = wave_sum64(y0[r] * y0[r] + y1[r] * y1[r]);
    float mu = s * 0.0078125f;
    float var = s2 * 0.0078125f - mu * mu;
    float rstd = rsqrtf(var + 1e-5f);
    y0[r] = (y0[r] - mu) * rstd * g0 + be0;
    y1[r] = (y1[r] - mu) * rstd * g1 + be1;
  }
}

// copy 8 contiguous rows of 128 floats (4KB) global -> LDS, one wave
__device__ __forceinline__ void copy8x128(const float* __restrict__ src,
                                          float* __restrict__ dst, int lane) {
#pragma unroll
  for (int t = 0; t < 4; ++t) {
    float4 v = ((const float4*)src)[lane + 64 * t];
    ((float4*)dst)[lane + 64 * t] = v;
  }
}

// ---------------- node MLPs: nw, mi, ii, de (128->128->1), full fp32 ----------------
__global__ __launch_bounds__(256) void k_node(
    const float* __restrict__ NL,
    const float* __restrict__ nw_W1, const float* __restrict__ nw_b1,
    const float* __restrict__ nw_W2, const float* __restrict__ nw_b2,
    const float* __restrict__ mi_W1, const float* __restrict__ mi_b1,
    const float* __restrict__ mi_W2, const float* __restrict__ mi_b2,
    const float* __restrict__ ii_W1, const float* __restrict__ ii_b1,
    const float* __restrict__ ii_W2, const float* __restrict__ ii_b2,
    const float* __restrict__ de_W1, const float* __restrict__ de_b1,
    const float* __restrict__ de_W2, const float* __restrict__ de_b2,
    float* __restrict__ o_nw, float* __restrict__ o_mi, float* __restrict__ o_ii,
    float* __restrict__ o_de) {
  __shared__ float xb[4][8 * 128];
  int w = threadIdx.x >> 6, l = threadIdx.x & 63;
  int nb = blockIdx.x * 32 + w * 8;
  copy8x128(NL + (size_t)nb * 128, xb[w], l);
  __syncthreads();
  const float* W1s[4] = {nw_W1, mi_W1, ii_W1, de_W1};
  const float* B1[4] = {nw_b1, mi_b1, ii_b1, de_b1};
  const float* W2[4] = {nw_W2, mi_W2, ii_W2, de_W2};
  const float* B2[4] = {nw_b2, mi_b2, ii_b2, de_b2};
  float* OUT[4] = {o_nw, o_mi, o_ii, o_de};
#pragma unroll
  for (int m = 0; m < 4; ++m) {
    float b10 = B1[m][l], b11 = B1[m][l + 64];
    float a0[8], a1[8];
#pragma unroll
    for (int r = 0; r < 8; ++r) { a0[r] = b10; a1[r] = b11; }
    gemv8(W1s[m], xb[w], 128, 128, l, a0, a1);
    float w2a = W2[m][l], w2b = W2[m][l + 64];
    float b2 = B2[m][0];
    float y[8];
#pragma unroll
    for (int r = 0; r < 8; ++r) {
      float p = fmaxf(a0[r], 0.f) * w2a + fmaxf(a1[r], 0.f) * w2b;
      y[r] = wave_sum64(p) + b2;
    }
    if (l == 0) {
#pragma unroll
      for (int r = 0; r < 8; ++r) OUT[m][nb + r] = y[r];
    }
  }
}

// ---------------- edge encoder (ee): [||dx||,||dt||,attr] -> 128, LN ----------------
__global__ __launch_bounds__(256) void k_ee(
    const float* __restrict__ dx, const float* __restrict__ dt, const float* __restrict__ attr,
    const float* __restrict__ W1, const float* __restrict__ b1,
    const float* __restrict__ W2, const float* __restrict__ b2,
    const float* __restrict__ g, const float* __restrict__ be, float* __restrict__ elat) {
  __shared__ float xb3[4][8 * 4];
  __shared__ float hb[4][8 * 128];
  int w = threadIdx.x >> 6, l = threadIdx.x & 63;
  int base = blockIdx.x * 32 + w * 8;
  if (l < 8) {
    int e = base + l;
    float a0 = dx[e * 3], a1v = dx[e * 3 + 1], a2 = dx[e * 3 + 2];
    float t0 = dt[e * 3], t1 = dt[e * 3 + 1], t2 = dt[e * 3 + 2];
    xb3[w][l * 4 + 0] = sqrtf(a0 * a0 + a1v * a1v + a2 * a2);
    xb3[w][l * 4 + 1] = sqrtf(t0 * t0 + t1 * t1 + t2 * t2);
    xb3[w][l * 4 + 2] = attr[e];
  }
  __syncthreads();
  float b10 = b1[l], b11 = b1[l + 64];
  float a0[8], a1[8];
#pragma unroll
  for (int r = 0; r < 8; ++r) { a0[r] = b10; a1[r] = b11; }
#pragma unroll
  for (int i = 0; i < 3; ++i) {
    float w0 = W1[i * 128 + l], w1 = W1[i * 128 + 64 + l];
#pragma unroll
    for (int r = 0; r < 8; ++r) {
      float xv = xb3[w][r * 4 + i];
      a0[r] = fmaf(xv, w0, a0[r]);
      a1[r] = fmaf(xv, w1, a1[r]);
    }
  }
#pragma unroll
  for (int r = 0; r < 8; ++r) {
    hb[w][r * 128 + l] = fmaxf(a0[r], 0.f);
    hb[w][r * 128 + 64 + l] = fmaxf(a1[r], 0.f);
  }
  __syncthreads();
  float y0[8], y1[8];
  float b20 = b2[l], b21 = b2[l + 64];
#pragma unroll
  for (int r = 0; r < 8; ++r) { y0[r] = b20; y1[r] = b21; }
  gemv8(W2, hb[w], 128, 128, l, y0, y1);
  layernorm8(y0, y1, g[l], g[l + 64], be[l], be[l + 64]);
#pragma unroll
  for (int r = 0; r < 8; ++r) {
    size_t o = (size_t)(base + r) * 128;
    elat[o + l] = y0[r];
    elat[o + 64 + l] = y1[r];
  }
}

// ---------------- edge-feature encoder (ef): 9 -> 128, LN; writes slr = s_lat + r_lat (bf16 pairs)
__global__ __launch_bounds__(256) void k_ef(
    const float* __restrict__ va, const float* __restrict__ vb, const float* __restrict__ vc,
    const float* __restrict__ svt, const float* __restrict__ svtm1, const float* __restrict__ swt,
    const float* __restrict__ rvt, const float* __restrict__ rvtm1, const float* __restrict__ rwt,
    const float* __restrict__ W1, const float* __restrict__ b1,
    const float* __restrict__ W2, const float* __restrict__ b2,
    const float* __restrict__ g, const float* __restrict__ be, uint32_t* __restrict__ slrp) {
  __shared__ float xb9[4][8 * 12];
  __shared__ float hb[4][8 * 128];
  int w = threadIdx.x >> 6, l = threadIdx.x & 63;
  int base = blockIdx.x * 16 + w * 4;  // 4 edges, rows 0..3 = sf, rows 4..7 = rf
  if (l < 8) {
    int e = base + (l & 3);
    bool isR = l >= 4;
    const float* p0 = isR ? rvt : svt;
    const float* p1 = isR ? rvtm1 : svtm1;
    const float* p2 = isR ? rwt : swt;
    float sgn = isR ? -1.f : 1.f;
    float ax = va[e * 3], ay = va[e * 3 + 1], az = va[e * 3 + 2];
    float bx = vb[e * 3], by = vb[e * 3 + 1], bz = vb[e * 3 + 2];
    float cx = vc[e * 3], cy = vc[e * 3 + 1], cz = vc[e * 3 + 2];
    const float* ps[3] = {p0, p1, p2};
#pragma unroll
    for (int q = 0; q < 3; ++q) {
      float vx = ps[q][e * 3], vy = ps[q][e * 3 + 1], vz = ps[q][e * 3 + 2];
      xb9[w][l * 12 + q * 3 + 0] = sgn * (vx * ax + vy * ay + vz * az);
      xb9[w][l * 12 + q * 3 + 1] = sgn * (vx * bx + vy * by + vz * bz);
      xb9[w][l * 12 + q * 3 + 2] = sgn * (vx * cx + vy * cy + vz * cz);
    }
  }
  __syncthreads();
  float b10 = b1[l], b11 = b1[l + 64];
  float a0[8], a1[8];
#pragma unroll
  for (int r = 0; r < 8; ++r) { a0[r] = b10; a1[r] = b11; }
#pragma unroll
  for (int i = 0; i < 9; ++i) {
    float w0 = W1[i * 128 + l], w1 = W1[i * 128 + 64 + l];
#pragma unroll
    for (int r = 0; r < 8; ++r) {
      float xv = xb9[w][r * 12 + i];
      a0[r] = fmaf(xv, w0, a0[r]);
      a1[r] = fmaf(xv, w1, a1[r]);
    }
  }
#pragma unroll
  for (int r = 0; r < 8; ++r) {
    hb[w][r * 128 + l] = fmaxf(a0[r], 0.f);
    hb[w][r * 128 + 64 + l] = fmaxf(a1[r], 0.f);
  }
  __syncthreads();
  float y0[8], y1[8];
  float b20 = b2[l], b21 = b2[l + 64];
#pragma unroll
  for (int r = 0; r < 8; ++r) { y0[r] = b20; y1[r] = b21; }
  gemv8(W2, hb[w], 128, 128, l, y0, y1);
  layernorm8(y0, y1, g[l], g[l + 64], be[l], be[l + 64]);
#pragma unroll
  for (int r = 0; r < 4; ++r) {
    float s0 = y0[r] + y0[r + 4];
    float s1 = y1[r] + y1[r + 4];
    slrp[(size_t)(base + r) * 64 + l] = f2bf16(s0) | (f2bf16(s1) << 16);
  }
}

// ---------------- interaction encoder (ie): 384 -> 128 -> 128, LN ----------------
__global__ __launch_bounds__(128) void k_ie(
    const int* __restrict__ ei, const float* __restrict__ NL,
    const uint32_t* __restrict__ slrp, const float* __restrict__ b1,
    const float* __restrict__ W1, const float* __restrict__ W2,
    const float* __restrict__ b2, const float* __restrict__ g, const float* __restrict__ be,
    float* __restrict__ il) {
  __shared__ float xb[2][8 * 384];
  __shared__ float hb[2][8 * 128];
  int w = threadIdx.x >> 6, l = threadIdx.x & 63;
  int base = blockIdx.x * 16 + w * 8;
#pragma unroll
  for (int r = 0; r < 8; ++r) {
    int e = base + r;
    uint32_t u = slrp[(size_t)e * 64 + l];
    xb[w][r * 384 + l] = bfu_lo(u);
    xb[w][r * 384 + 64 + l] = bfu_hi(u);
    int s = ei[e], t = ei[E_EDGES + e];
    xb[w][r * 384 + 128 + l] = NL[(size_t)s * 128 + l] + NL[(size_t)t * 128 + l];
    xb[w][r * 384 + 192 + l] = NL[(size_t)s * 128 + 64 + l] + NL[(size_t)t * 128 + 64 + l];
    const float* er = il + (size_t)e * 128;  // e_lat staged by k_ee
    xb[w][r * 384 + 256 + l] = er[l];
    xb[w][r * 384 + 320 + l] = er[64 + l];
  }
  __syncthreads();
  float b10 = b1[l], b11 = b1[l + 64];
  float a0[8], a1[8];
#pragma unroll
  for (int r = 0; r < 8; ++r) { a0[r] = b10; a1[r] = b11; }
  gemv8(W1, xb[w], 384, 384, l, a0, a1);
#pragma unroll
  for (int r = 0; r < 8; ++r) {
    hb[w][r * 128 + l] = fmaxf(a0[r], 0.f);
    hb[w][r * 128 + 64 + l] = fmaxf(a1[r], 0.f);
  }
  __syncthreads();
  float y0[8], y1[8];
  float b20 = b2[l], b21 = b2[l + 64];
#pragma unroll
  for (int r = 0; r < 8; ++r) { y0[r] = b20; y1[r] = b21; }
  gemv8(W2, hb[w], 128, 128, l, y0, y1);
  layernorm8(y0, y1, g[l], g[l + 64], be[l], be[l + 64]);
#pragma unroll
  for (int r = 0; r < 8; ++r) {
    size_t o = (size_t)(base + r) * 128;
    il[o + l] = y0[r];
    il[o + 64 + l] = y1[r];
  }
}

// ---------------- decoder heads + physics + scatter ----------------
template <int NK>
__device__ __forceinline__ void dec_mlp(const float* __restrict__ W1,
                                        const float* __restrict__ b1,
                                        const float* __restrict__ W2,
                                        const float* __restrict__ b2,
                                        const float* __restrict__ xbw, float* __restrict__ dbw,
                                        int l, int slot0) {
  float b10 = b1[l], b11 = b1[l + 64];
  float a0[8], a1[8];
#pragma unroll
  for (int r = 0; r < 8; ++r) { a0[r] = b10; a1[r] = b11; }
  gemv8(W1, xbw, 128, 128, l, a0, a1);
  float w2lo[NK], w2hi[NK];
#pragma unroll
  for (int k = 0; k < NK; ++k) {
    w2lo[k] = W2[l * NK + k];
    w2hi[k] = W2[(l + 64) * NK + k];
  }
#pragma unroll
  for (int r = 0; r < 8; ++r) {
    float h0 = fmaxf(a0[r], 0.f), h1 = fmaxf(a1[r], 0.f);
#pragma unroll
    for (int k = 0; k < NK; ++k) {
      float p = wave_sum64(h0 * w2lo[k] + h1 * w2hi[k]);
      if (l == 0) dbw[r * 8 + slot0 + k] = p + b2[k];
    }
  }
}

__global__ __launch_bounds__(256) void k_dec(
    const int* __restrict__ ei, const float* __restrict__ il,
    const float* __restrict__ i1W1, const float* __restrict__ i1b1,
    const float* __restrict__ i1W2, const float* __restrict__ i1b2,
    const float* __restrict__ i2W1, const float* __restrict__ i2b1,
    const float* __restrict__ i2W2, const float* __restrict__ i2b2,
    const float* __restrict__ fsW1, const float* __restrict__ fsb1,
    const float* __restrict__ fsW2, const float* __restrict__ fsb2,
    const float* __restrict__ nw, const float* __restrict__ spos, const float* __restrict__ rpos,
    const float* __restrict__ va, const float* __restrict__ vb, const float* __restrict__ vc,
    float* __restrict__ fsum, float* __restrict__ tsum) {
  __shared__ float xb[4][8 * 128];
  __shared__ float db[4][8 * 8];  // per row: 0-2 coeff_f, 3-5 coeff_a, 6 lambda
  int w = threadIdx.x >> 6, l = threadIdx.x & 63;
  int base = blockIdx.x * 32 + w * 8;
  copy8x128(il + (size_t)base * 128, xb[w], l);
  __syncthreads();
  dec_mlp<3>(i1W1, i1b1, i1W2, i1b2, xb[w], db[w], l, 0);
  dec_mlp<3>(i2W1, i2b1, i2W2, i2b2, xb[w], db[w], l, 3);
  dec_mlp<1>(fsW1, fsb1, fsW2, fsb2, xb[w], db[w], l, 6);
  __syncthreads();
  if (l < 8) {
    int e = base + l;
    int s = ei[e], t = ei[E_EDGES + e];
    float cf0 = db[w][l * 8 + 0], cf1 = db[w][l * 8 + 1], cf2 = db[w][l * 8 + 2];
    float ca0 = db[w][l * 8 + 3], ca1 = db[w][l * 8 + 4], ca2 = db[w][l * 8 + 5];
    float lam = db[w][l * 8 + 6];
    float ax = va[e * 3], ay = va[e * 3 + 1], az = va[e * 3 + 2];
    float bx = vb[e * 3], by = vb[e * 3 + 1], bz = vb[e * 3 + 2];
    float cx = vc[e * 3], cy = vc[e * 3 + 1], cz = vc[e * 3 + 2];
    float fx = cf0 * ax + cf1 * bx + cf2 * cx;
    float fy = cf0 * ay + cf1 * by + cf2 * cy;
    float fz = cf0 * az + cf1 * bz + cf2 * cz;
    float gx = ca0 * ax + ca1 * bx + ca2 * cx;
    float gy = ca0 * ay + ca1 * by + ca2 * cy;
    float gz = ca0 * az + ca1 * bz + ca2 * cz;
    float wsn = nw[s], wrn = nw[t];
    float sx = spos[e * 3], sy = spos[e * 3 + 1], sz = spos[e * 3 + 2];
    float rx = rpos[e * 3], ry = rpos[e * 3 + 1], rz = rpos[e * 3 + 2];
    float inv = 1.f / (wsn + wrn);
    float r0x = (wsn * sx + wrn * rx) * inv;
    float r0y = (wsn * sy + wrn * ry) * inv;
    float r0z = (wsn * sz + wrn * rz) * inv;
    float ddx = rx - r0x, ddy = ry - r0y, ddz = rz - r0z;
    float cxx = ddy * fz - ddz * fy;
    float cyy = ddz * fx - ddx * fz;
    float czz = ddx * fy - ddy * fx;
    float tx = gx - cxx * lam, ty = gy - cyy * lam, tz = gz - czz * lam;
    atomicAdd(&fsum[(size_t)t * 3 + 0], fx);
    atomicAdd(&fsum[(size_t)t * 3 + 1], fy);
    atomicAdd(&fsum[(size_t)t * 3 + 2], fz);
    atomicAdd(&tsum[(size_t)t * 3 + 0], tx);
    atomicAdd(&tsum[(size_t)t * 3 + 1], ty);
    atomicAdd(&tsum[(size_t)t * 3 + 2], tz);
  }
}

// ---------------- final node combine ----------------
__global__ __launch_bounds__(256) void k_final(const float* __restrict__ mi,
                                               const float* __restrict__ ii,
                                               const float* __restrict__ de,
                                               const float* __restrict__ fsum,
                                               const float* __restrict__ tsum,
                                               float* __restrict__ out) {
  int n = blockIdx.x * 256 + threadIdx.x;
  if (n >= N_NODES) return;
  float m = mi[n], iv = ii[n], d = de[n];
#pragma unroll
  for (int c = 0; c < 3; ++c) {
    out[(size_t)n * 3 + c] = m * fsum[(size_t)n * 3 + c] + d;
    out[(size_t)3 * N_NODES + (size_t)n * 3 + c] = iv * tsum[(size_t)n * 3 + c];
  }
}

// ---------------- launch ----------------
extern "C" void kernel_launch(void* const* d_in, const int* in_sizes, int n_in, void* d_out,
                              int out_size, void* d_ws, size_t ws_size, hipStream_t stream) {
  if (ws_size < WSEND) return;  // insufficient scratch; bail (will show as wrong output)

  const int* ei = (const int*)d_in[0];
  const float* spos = (const float*)d_in[1];
  const float* rpos = (const float*)d_in[2];
  const float* dx = (const float*)d_in[3];
  const float* dt = (const float*)d_in[4];
  const float* va = (const float*)d_in[5];
  const float* vb = (const float*)d_in[6];
  const float* vc = (const float*)d_in[7];
  const float* svt = (const float*)d_in[8];
  const float* svtm1 = (const float*)d_in[9];
  const float* swt = (const float*)d_in[10];
  const float* rvt = (const float*)d_in[11];
  const float* rvtm1 = (const float*)d_in[12];
  const float* rwt = (const float*)d_in[13];
  const float* attr = (const float*)d_in[14];
  const float* NL = (const float*)d_in[15];
  const float* ef_W1 = (const float*)d_in[16];
  const float* ef_b1 = (const float*)d_in[17];
  const float* ef_W2 = (const float*)d_in[18];
  const float* ef_b2 = (const float*)d_in[19];
  const float* ef_g = (const float*)d_in[20];
  const float* ef_b = (const float*)d_in[21];
  const float* ee_W1 = (const float*)d_in[22];
  const float* ee_b1 = (const float*)d_in[23];
  const float* ee_W2 = (const float*)d_in[24];
  const float* ee_b2 = (const float*)d_in[25];
  const float* ee_g = (const float*)d_in[26];
  const float* ee_b = (const float*)d_in[27];
  const float* ie_W1 = (const float*)d_in[28];
  const float* ie_b1 = (const float*)d_in[29];
  const float* ie_W2 = (const float*)d_in[30];
  const float* ie_b2 = (const float*)d_in[31];
  const float* ie_g = (const float*)d_in[32];
  const float* ie_b = (const float*)d_in[33];
  const float* i1_W1 = (const float*)d_in[34];
  const float* i1_b1 = (const float*)d_in[35];
  const float* i1_W2 = (const float*)d_in[36];
  const float* i1_b2 = (const float*)d_in[37];
  const float* i2_W1 = (const float*)d_in[38];
  const float* i2_b1 = (const float*)d_in[39];
  const float* i2_W2 = (const float*)d_in[40];
  const float* i2_b2 = (const float*)d_in[41];
  const float* fs_W1 = (const float*)d_in[42];
  const float* fs_b1 = (const float*)d_in[43];
  const float* fs_W2 = (const float*)d_in[44];
  const float* fs_b2 = (const float*)d_in[45];
  const float* nw_W1 = (const float*)d_in[46];
  const float* nw_b1 = (const float*)d_in[47];
  const float* nw_W2 = (const float*)d_in[48];
  const float* nw_b2 = (const float*)d_in[49];
  const float* mi_W1 = (const float*)d_in[50];
  const float* mi_b1 = (const float*)d_in[51];
  const float* mi_W2 = (const float*)d_in[52];
  const float* mi_b2 = (const float*)d_in[53];
  const float* ii_W1 = (const float*)d_in[54];
  const float* ii_b1 = (const float*)d_in[55];
  const float* ii_W2 = (const float*)d_in[56];
  const float* ii_b2 = (const float*)d_in[57];
  const float* de_W1 = (const float*)d_in[58];
  const float* de_b1 = (const float*)d_in[59];
  const float* de_W2 = (const float*)d_in[60];
  const float* de_b2 = (const float*)d_in[61];

  float* out = (float*)d_out;
  char* ws = (char*)d_ws;
  uint32_t* slrp = (uint32_t*)(ws + OSLR);
  float* o_nw = (float*)(ws + ONW);
  float* o_mi = (float*)(ws + OMI);
  float* o_ii = (float*)(ws + OII);
  float* o_de = (float*)(ws + ODE);
  float* fsum = (float*)(ws + OFS);
  float* tsum = (float*)(ws + OTS);
  float* il = out + 6 * N_NODES;  // interaction_latent region (also e_lat temp)

  hipMemsetAsync(ws + OFS, 0, (size_t)N_NODES * 24, stream);  // fsum + tsum

  hipLaunchKernelGGL(k_node, dim3(N_NODES / 32), dim3(256), 0, stream, NL,
                     nw_W1, nw_b1, nw_W2, nw_b2, mi_W1, mi_b1, mi_W2, mi_b2,
                     ii_W1, ii_b1, ii_W2, ii_b2, de_W1, de_b1, de_W2, de_b2,
                     o_nw, o_mi, o_ii, o_de);

  hipLaunchKernelGGL(k_ee, dim3(E_EDGES / 32), dim3(256), 0, stream, dx, dt, attr, ee_W1, ee_b1,
                     ee_W2, ee_b2, ee_g, ee_b, il);

  hipLaunchKernelGGL(k_ef, dim3(E_EDGES / 16), dim3(256), 0, stream, va, vb, vc, svt, svtm1, swt,
                     rvt, rvtm1, rwt, ef_W1, ef_b1, ef_W2, ef_b2, ef_g, ef_b, slrp);

  hipLaunchKernelGGL(k_ie, dim3(E_EDGES / 16), dim3(128), 0, stream, ei, NL, slrp, ie_b1,
                     ie_W1, ie_W2, ie_b2, ie_g, ie_b, il);

  hipLaunchKernelGGL(k_dec, dim3(E_EDGES / 32), dim3(256), 0, stream, ei, il, i1_W1, i1_b1,
                     i1_W2, i1_b2, i2_W1, i2_b1, i2_W2, i2_b2, fs_W1, fs_b1, fs_W2,
                     fs_b2, o_nw, spos, rpos, va, vb, vc, fsum, tsum);

  hipLaunchKernelGGL(k_final, dim3((N_NODES + 255) / 256), dim3(256), 0, stream, o_mi, o_ii, o_de,
                     fsum, tsum, out);
}